// Round 1
// baseline (208.565 us; speedup 1.0000x reference)
//
#include <hip/hip_runtime.h>

// Problem constants (fixed by reference setup_inputs):
//   x: (B=4, C=64, H=512, W=512) fp32
//   conv1_weight: (C, 1, 5) fp32   -- depthwise FIR, SAME pad (2 each side), cross-correlation
//   conv2_weight: (C, 3) fp32      -- IIR feedback: y[j] = f[j] - (w[0]*y[j-3] + w[1]*y[j-2] + w[2]*y[j-1])
constexpr int Wd  = 512;
constexpr int Cc  = 64;
constexpr int Hh  = 512;
constexpr int CH  = 32;            // columns per chunk
constexpr int RB  = 128;           // rows per block == blockDim.x
constexpr int NCHUNK = Wd / CH;    // 16
constexpr int STRIDE = CH + 1;     // 33: odd -> conflict-free row-private LDS access

__global__ __launch_bounds__(RB)
void iir_conv2d_kernel(const float* __restrict__ x,
                       const float* __restrict__ w1,   // (C,1,5)
                       const float* __restrict__ w2,   // (C,3)
                       float* __restrict__ y)
{
    __shared__ float xs[RB * STRIDE];   // 16.9 KB, reused for x-window then y in place

    const int tid  = threadIdx.x;
    const int row0 = blockIdx.x * RB;          // 128 rows per block; 128 | H so c is block-uniform
    const int myrow = row0 + tid;
    const int c = (myrow >> 9) & (Cc - 1);     // row = (b*C + c)*H + h, H=512, C=64

    const float a0 = w1[c * 5 + 0], a1 = w1[c * 5 + 1], a2 = w1[c * 5 + 2],
                a3 = w1[c * 5 + 3], a4 = w1[c * 5 + 4];
    const float v0 = w2[c * 3 + 0], v1 = w2[c * 3 + 1], v2 = w2[c * 3 + 2];

    // FIR input pipeline (x[j-2..j+1]) and IIR state (y[j-3..j-1]); zero left padding.
    const float* xrow = x + (size_t)myrow * Wd;
    float xm2 = 0.f, xm1 = 0.f, x0 = xrow[0], xp1 = xrow[1];
    float ym3 = 0.f, ym2 = 0.f, ym1 = 0.f;

    for (int ci = 0; ci < NCHUNK; ++ci) {
        const int c0 = ci * CH;

        // ---- Load phase: window [c0+2, c0+CH+2) for 128 rows, coalesced ----
        #pragma unroll
        for (int it = 0; it < CH; ++it) {
            const int e   = it * RB + tid;
            const int r   = e >> 5;            // e / CH
            const int col = e & (CH - 1);      // e % CH
            const int gcol = c0 + 2 + col;
            float v = 0.f;
            if (gcol < Wd) v = x[(size_t)(row0 + r) * Wd + gcol];
            xs[r * STRIDE + col] = v;
        }
        __syncthreads();

        // ---- Compute phase: row-private, sequential; y overwrites x slot in place ----
        #pragma unroll
        for (int jj = 0; jj < CH; ++jj) {
            const float xp2 = xs[tid * STRIDE + jj];            // x[j+2]
            const float f = a0 * xm2 + a1 * xm1 + a2 * x0 + a3 * xp1 + a4 * xp2;
            const float yv = f - (v0 * ym3 + v1 * ym2 + v2 * ym1);
            xs[tid * STRIDE + jj] = yv;                         // y[j] (slot dead after read)
            xm2 = xm1; xm1 = x0; x0 = xp1; xp1 = xp2;
            ym3 = ym2; ym2 = ym1; ym1 = yv;
        }
        __syncthreads();

        // ---- Store phase: columns [c0, c0+CH), coalesced 128B segments ----
        #pragma unroll
        for (int it = 0; it < CH; ++it) {
            const int e   = it * RB + tid;
            const int r   = e >> 5;
            const int col = e & (CH - 1);
            y[(size_t)(row0 + r) * Wd + c0 + col] = xs[r * STRIDE + col];
        }
        __syncthreads();
    }
}

extern "C" void kernel_launch(void* const* d_in, const int* in_sizes, int n_in,
                              void* d_out, int out_size, void* d_ws, size_t ws_size,
                              hipStream_t stream) {
    const float* x  = (const float*)d_in[0];
    const float* w1 = (const float*)d_in[1];
    const float* w2 = (const float*)d_in[2];
    float* y = (float*)d_out;

    const int rows = out_size / Wd;            // B*C*H = 131072
    const int blocks = rows / RB;              // 1024
    iir_conv2d_kernel<<<blocks, RB, 0, stream>>>(x, w1, w2, y);
}